// Round 18
// baseline (67.047 us; speedup 1.0000x reference)
//
#include <hip/hip_runtime.h>
#include <hip/hip_bf16.h>

// Head attention: x[4,4096,1024] f32, Wq/Wk/Wv[1024,64] f32 -> out[4,4096,64] f32
// v18 = v17's wtf/proj + attn64: 64 q-rows/block (halves KV L2 traffic,
//   attnW's binding constraint: 512->256 MB). Lean body kept from v15:
//   swapped QK^T, raw exp2, packed cvt_pk P writes, ones-MFMA l.
//   launch_bounds(512,2): 256-VGPR budget, grid 256 = 1 block/CU.

#define BB 4
#define TT 4096
#define CC 1024
#define HH 64

typedef __attribute__((ext_vector_type(8))) short bf16x8;
typedef __attribute__((ext_vector_type(4))) float f32x4;

#if __has_builtin(__builtin_amdgcn_exp2f)
#define EXP2(x) __builtin_amdgcn_exp2f(x)
#else
#define EXP2(x) exp2f(x)
#endif

__device__ __forceinline__ short f2bf(float f) {
  union { float f; unsigned u; } v; v.f = f;
  unsigned r = v.u + 0x7fffu + ((v.u >> 16) & 1u);  // RNE
  return (short)(r >> 16);
}

__device__ __forceinline__ unsigned pk2bf(float lo, float hi) {  // packed RNE cvt
  __hip_bfloat162 p = __float22bfloat162_rn(make_float2(lo, hi));
  return *reinterpret_cast<unsigned*>(&p);
}

// ---------------- wtf: W -> WtF[nf 12][ks 32][lane 64][8] bf16 ---------------
// q part scaled by C^-0.5 * log2(e)  (softmax exp == exp2 of logits)
__global__ void wtf_kernel(const float* __restrict__ Wq, const float* __restrict__ Wk,
                           const float* __restrict__ Wv, short* __restrict__ WtF) {
  int idx = blockIdx.x * 256 + threadIdx.x;       // 24576
  int lane = idx & 63, ks = (idx >> 6) & 31, nf = idx >> 11;
  int l15 = lane & 15, lg = lane >> 4;
  int n = nf * 16 + l15;
  const float* W = (n < HH) ? Wq : ((n < 2 * HH) ? Wk : Wv);
  float sc = (n < HH) ? (0.03125f * 1.44269504f) : 1.0f;
  int k0 = ks * 32 + lg * 8, h = n & (HH - 1);
  bf16x8 r;
#pragma unroll
  for (int j = 0; j < 8; ++j) r[j] = f2bf(W[(k0 + j) * HH + h] * sc);
  *(bf16x8*)(WtF + (size_t)idx * 8) = r;
}

// ---------------- proj: fused staging + nf-split MFMA + frag-order epilogue --
// (byte-identical to v17)
__launch_bounds__(256, 4)
__global__ void proj_kernel(const float* __restrict__ x, const short* __restrict__ WtF,
                            short* __restrict__ qo, short* __restrict__ kFo,
                            short* __restrict__ vFo) {
  __shared__ __align__(16) short xs[16 * 1024];   // 32 KB (reused by epilogue)
  int t = threadIdx.x;
  int row0 = blockIdx.x * 16;

  {  // stage x[16][1024] f32 -> bf16 frag-order LDS, XOR-swizzled, packed cvt
    int r = t >> 4, kc = t & 15;
    const float4* xr4 = (const float4*)(x + (size_t)(row0 + r) * CC) + kc * 2;
#pragma unroll
    for (int i = 0; i < 8; ++i) {
      float4 a = xr4[i * 32], b2 = xr4[i * 32 + 1];
      uint4 w;
      w.x = pk2bf(a.x, a.y);   w.y = pk2bf(a.z, a.w);
      w.z = pk2bf(b2.x, b2.y); w.w = pk2bf(b2.z, b2.w);
      int c = kc + i * 16;
      int S = (c * 256 + r * 16) ^ ((c & 7) << 4);
      *(uint4*)((char*)xs + S) = w;
    }
  }
  __syncthreads();

  int wave = t >> 6, lane = t & 63;
  int l15 = lane & 15, lg = lane >> 4;
  int nf0 = wave * 3;
  const short* wp = WtF + ((size_t)nf0 * 32 * 64 + (size_t)lane) * 8;
  const char* xsb = (const char*)xs;

  f32x4 acc[3];
#pragma unroll
  for (int j = 0; j < 3; ++j) acc[j] = (f32x4){0.f, 0.f, 0.f, 0.f};

  bf16x8 wA[3], wB[3];
#pragma unroll
  for (int j = 0; j < 3; ++j) wA[j] = *(const bf16x8*)(wp + (size_t)j * 32 * 512);

#pragma unroll
  for (int ks = 0; ks < 32; ks += 2) {
#pragma unroll
    for (int j = 0; j < 3; ++j)
      wB[j] = *(const bf16x8*)(wp + ((size_t)j * 32 + ks + 1) * 512);
    bf16x8 a0 = *(const bf16x8*)(xsb + ks * 1024 +
                   ((lane * 16) ^ ((((ks * 4) + lg) & 7) << 4)));
#pragma unroll
    for (int j = 0; j < 3; ++j)
      acc[j] = __builtin_amdgcn_mfma_f32_16x16x32_bf16(a0, wA[j], acc[j], 0, 0, 0);
    if (ks + 2 < 32) {
#pragma unroll
      for (int j = 0; j < 3; ++j)
        wA[j] = *(const bf16x8*)(wp + ((size_t)j * 32 + ks + 2) * 512);
    }
    bf16x8 a1 = *(const bf16x8*)(xsb + (ks + 1) * 1024 +
                   ((lane * 16) ^ (((((ks + 1) * 4) + lg) & 7) << 4)));
#pragma unroll
    for (int j = 0; j < 3; ++j)
      acc[j] = __builtin_amdgcn_mfma_f32_16x16x32_bf16(a1, wB[j], acc[j], 0, 0, 0);
  }

  // ---- epilogue ----
  int b  = row0 >> 12;
  int kt = (row0 & 4095) >> 6;
  int cf = (row0 >> 4) & 3;
  short* ksl = xs;           // k stage: [16 rows][72]  (144B rows, 16B-aligned)
  short* vsl = xs + 1152;    // v stage: [64 h][24]     (48B rows)

  __syncthreads();           // xs (MFMA operand region) is dead; reuse for stage

#pragma unroll
  for (int j = 0; j < 3; ++j) {
    int nf = nf0 + j;
    int h = (nf & 3) * 16 + l15;
    if (nf < 4) {            // q: row-major global
#pragma unroll
      for (int reg = 0; reg < 4; ++reg)
        qo[(size_t)(row0 + lg * 4 + reg) * HH + h] = f2bf(acc[j][reg]);
    } else if (nf < 8) {     // k: stage [row][h], stride 72
#pragma unroll
      for (int reg = 0; reg < 4; ++reg)
        ksl[(lg * 4 + reg) * 72 + h] = f2bf(acc[j][reg]);
    } else {                 // v: stage transposed [h][row], packed
      uint2 w2;
      w2.x = pk2bf(acc[j][0], acc[j][1]);
      w2.y = pk2bf(acc[j][2], acc[j][3]);
      *(uint2*)(vsl + h * 24 + lg * 4) = w2;
    }
  }
  __syncthreads();

  size_t tileoff = ((size_t)b * 64 + kt) * 4096;
  if (t < 128) {             // kF chunks ld = cf*2 + ks2 (full)
    int ks2 = t >> 6, ln = t & 63;
    int l15o = ln & 15, lgo = ln >> 4;
    bf16x8 r = *(const bf16x8*)(ksl + l15o * 72 + ks2 * 32 + lgo * 8);
    *(bf16x8*)(kFo + tileoff + (size_t)(cf * 2 + ks2) * 512 + ln * 8) = r;
  } else if (t < 256) {      // vF chunks ld = hf*2 + (cf>>1), lanes lg-subset
    int t2 = t - 128;
    int hf = t2 >> 5, lgl = (t2 >> 4) & 1, l15o = t2 & 15;
    bf16x8 r = *(const bf16x8*)(vsl + (hf * 16 + l15o) * 24 + lgl * 8);
    int lnout = (2 * (cf & 1) + lgl) * 16 + l15o;
    *(bf16x8*)(vFo + tileoff + (size_t)(hf * 2 + (cf >> 1)) * 512 + lnout * 8) = r;
  }
}

// ---------------- attn64: 64-row blocks, 8-way KV split, lean VALU -----------
// grid 256 x 512 thr (8 waves = 1 block/CU). Wave w = kv slice
// [w*512, w*512+512), 16 iters x 32 kv, covering ALL 64 block q-rows
// (4 groups of 16) -> KV bytes amortized over 2x the rows vs v15.
// Swapped QK^T (kv on reg axis), raw exp2, packed cvt_pk P writes,
// ones-MFMA l. 8-phase barrier merge; 64-row normalize.
__launch_bounds__(512, 2)
__global__ void attn64_kernel(const short* __restrict__ q, const short* __restrict__ kF,
                              const short* __restrict__ vF, float* __restrict__ out) {
  __shared__ __align__(16) short ps[8][5120];     // 80 KB: 4 P-tiles/wave, 80B rows
  __shared__ __align__(16) float macc[64][68];    // 17.4 KB merge O
  __shared__ float lL[64];
  int wave = threadIdx.x >> 6, lane = threadIdx.x & 63;
  int l15 = lane & 15, lg = lane >> 4;
  int low3 = blockIdx.x & 7;                 // XCD id (perf heuristic only)
  int b  = low3 >> 1;                        // 2 XCDs per batch -> L2-resident KV
  int qt = ((blockIdx.x >> 3) << 1) | (low3 & 1);   // 0..63
  int brow0 = qt * 64;

  const short* qb = q + ((size_t)b * TT + brow0 + l15) * HH;
  bf16x8 qa[4][2];
#pragma unroll
  for (int g = 0; g < 4; ++g) {
    qa[g][0] = *(const bf16x8*)(qb + g * 16 * HH + lg * 8);
    qa[g][1] = *(const bf16x8*)(qb + g * 16 * HH + 32 + lg * 8);
  }

  bf16x8 ones;
#pragma unroll
  for (int j = 0; j < 8; ++j) ones[j] = (short)0x3F80;   // bf16 1.0

  const short* kfb = kF + (size_t)b * 262144 + (size_t)lane * 8;
  const short* vfb = vF + (size_t)b * 262144 + (size_t)lane * 8;

  f32x4 acc[4][4], accl[4];
#pragma unroll
  for (int g = 0; g < 4; ++g) {
#pragma unroll
    for (int i = 0; i < 4; ++i) acc[g][i] = (f32x4){0.f, 0.f, 0.f, 0.f};
    accl[g] = (f32x4){0.f, 0.f, 0.f, 0.f};
  }

  char* psw = (char*)&ps[wave][0];
  int xorv = (l15 >> 3) << 4;
  int pwbase = l15 * 80;                       // write row = l15 (qrow)
  int pr = l15 * 80 + ((lg << 4) ^ xorv);      // read: row=l15, colbytes lg*16..+15

  for (int t = wave * 16; t < wave * 16 + 16; ++t) {
    const short* kp = kfb + (size_t)t * 2048;
    const short* vp = vfb + (size_t)(t >> 1) * 4096 + (size_t)(t & 1) * 512;
    bf16x8 kf[4], vf[4];
#pragma unroll
    for (int ld = 0; ld < 4; ++ld) kf[ld] = *(const bf16x8*)(kp + ld * 512);
#pragma unroll
    for (int hf = 0; hf < 4; ++hf) vf[hf] = *(const bf16x8*)(vp + hf * 1024);
    // ---- S^T = K q^T (kv on reg axis); p = exp2; packed pair writes ----
#pragma unroll
    for (int g = 0; g < 4; ++g)
#pragma unroll
      for (int cf = 0; cf < 2; ++cf) {
        f32x4 t4 = (f32x4){0.f, 0.f, 0.f, 0.f};
        t4 = __builtin_amdgcn_mfma_f32_16x16x32_bf16(kf[cf * 2], qa[g][0], t4, 0, 0, 0);
        t4 = __builtin_amdgcn_mfma_f32_16x16x32_bf16(kf[cf * 2 + 1], qa[g][1], t4, 0, 0, 0);
        float p0 = EXP2(t4[0]), p1 = EXP2(t4[1]);
        float p2 = EXP2(t4[2]), p3 = EXP2(t4[3]);
        unsigned w01 = pk2bf(p0, p1);
        unsigned w23 = pk2bf(p2, p3);
        int cb = (cf << 5) + (lg << 3);        // column byte = kv*2
        *(unsigned*)(psw + g * 1280 + pwbase + ((cb) ^ xorv)) = w01;
        *(unsigned*)(psw + g * 1280 + pwbase + ((cb + 4) ^ xorv)) = w23;
      }
    // ---- O += P V ; l += P . 1 ----
    __builtin_amdgcn_s_setprio(1);
#pragma unroll
    for (int g = 0; g < 4; ++g) {
      bf16x8 pa = *(const bf16x8*)(psw + g * 1280 + pr);
#pragma unroll
      for (int hf = 0; hf < 4; ++hf)
        acc[g][hf] = __builtin_amdgcn_mfma_f32_16x16x32_bf16(pa, vf[hf], acc[g][hf], 0, 0, 0);
      accl[g] = __builtin_amdgcn_mfma_f32_16x16x32_bf16(pa, ones, accl[g], 0, 0, 0);
    }
    __builtin_amdgcn_s_setprio(0);
  }

  // ---- merge 8 KV-eighths: sequential-barrier LDS accumulation ----
#pragma unroll
  for (int ph = 0; ph < 8; ++ph) {
    if (wave == ph) {
#pragma unroll
      for (int g = 0; g < 4; ++g)
#pragma unroll
        for (int reg = 0; reg < 4; ++reg) {
          int row = g * 16 + lg * 4 + reg;
          if (ph == 0) {
#pragma unroll
            for (int hf = 0; hf < 4; ++hf)
              macc[row][hf * 16 + l15] = acc[g][hf][reg];
            if (l15 == 0) lL[row] = accl[g][reg];
          } else {
#pragma unroll
            for (int hf = 0; hf < 4; ++hf)
              macc[row][hf * 16 + l15] += acc[g][hf][reg];
            if (l15 == 0) lL[row] += accl[g][reg];
          }
        }
    }
    __syncthreads();
  }

  // ---- normalize + store (64 rows x 64 cols = 8 f32/thread) ----
  {
    int tt = threadIdx.x;
    int r = tt >> 3, c0 = (tt & 7) * 8;
    float linv = 1.0f / lL[r];
    float4 o0, o1;
    o0.x = macc[r][c0 + 0] * linv; o0.y = macc[r][c0 + 1] * linv;
    o0.z = macc[r][c0 + 2] * linv; o0.w = macc[r][c0 + 3] * linv;
    o1.x = macc[r][c0 + 4] * linv; o1.y = macc[r][c0 + 5] * linv;
    o1.z = macc[r][c0 + 6] * linv; o1.w = macc[r][c0 + 7] * linv;
    float* op = out + ((size_t)b * TT + brow0 + r) * HH + c0;
    *(float4*)op = o0;
    *(float4*)(op + 4) = o1;
  }
}

extern "C" void kernel_launch(void* const* d_in, const int* in_sizes, int n_in,
                              void* d_out, int out_size, void* d_ws, size_t ws_size,
                              hipStream_t stream) {
  const float* x  = (const float*)d_in[0];
  const float* Wq = (const float*)d_in[1];
  const float* Wk = (const float*)d_in[2];
  const float* Wv = (const float*)d_in[3];
  float* out = (float*)d_out;

  char* ws = (char*)d_ws;
  short* WtF = (short*)ws;                 // 384 KB (pad to 512K)
  short* q   = (short*)(ws + 0x080000);    // 2 MB
  short* kF  = (short*)(ws + 0x280000);    // 2 MB
  short* vF  = (short*)(ws + 0x480000);    // 2 MB -> 6.5 MB total

  hipLaunchKernelGGL(wtf_kernel,    dim3(96),   dim3(256), 0, stream, Wq, Wk, Wv, WtF);
  hipLaunchKernelGGL(proj_kernel,   dim3(1024), dim3(256), 0, stream, x, WtF, q, kF, vF);
  hipLaunchKernelGGL(attn64_kernel, dim3(256),  dim3(512), 0, stream, q, kF, vF, out);
}

// Round 19
// 63.428 us; speedup vs baseline: 1.0571x; 1.0571x over previous
//
#include <hip/hip_runtime.h>
#include <hip/hip_bf16.h>

// Head attention: x[4,4096,1024] f32, Wq/Wk/Wv[1024,64] f32 -> out[4,4096,64] f32
// v19 = v17's wtf/attnW + proj32: 32-row proj blocks (halves WtF L2 re-reads,
//   proj's binding constraint per R19 arithmetic). Unlike failed v15: NO
//   K-split -- single 64KB stage + v14's exact dbuf loop (2 A-frags x 3 MFMA
//   per ks); v15's verified 32-row epilogue reused verbatim.
//   launch_bounds(256,2): 2 blocks/CU (64KB LDS), 256-VGPR budget.

#define BB 4
#define TT 4096
#define CC 1024
#define HH 64

typedef __attribute__((ext_vector_type(8))) short bf16x8;
typedef __attribute__((ext_vector_type(4))) float f32x4;

#if __has_builtin(__builtin_amdgcn_exp2f)
#define EXP2(x) __builtin_amdgcn_exp2f(x)
#else
#define EXP2(x) exp2f(x)
#endif

__device__ __forceinline__ short f2bf(float f) {
  union { float f; unsigned u; } v; v.f = f;
  unsigned r = v.u + 0x7fffu + ((v.u >> 16) & 1u);  // RNE
  return (short)(r >> 16);
}

__device__ __forceinline__ unsigned pk2bf(float lo, float hi) {  // packed RNE cvt
  __hip_bfloat162 p = __float22bfloat162_rn(make_float2(lo, hi));
  return *reinterpret_cast<unsigned*>(&p);
}

// ---------------- wtf: W -> WtF[nf 12][ks 32][lane 64][8] bf16 ---------------
// q part scaled by C^-0.5 * log2(e)  (softmax exp == exp2 of logits)
__global__ void wtf_kernel(const float* __restrict__ Wq, const float* __restrict__ Wk,
                           const float* __restrict__ Wv, short* __restrict__ WtF) {
  int idx = blockIdx.x * 256 + threadIdx.x;       // 24576
  int lane = idx & 63, ks = (idx >> 6) & 31, nf = idx >> 11;
  int l15 = lane & 15, lg = lane >> 4;
  int n = nf * 16 + l15;
  const float* W = (n < HH) ? Wq : ((n < 2 * HH) ? Wk : Wv);
  float sc = (n < HH) ? (0.03125f * 1.44269504f) : 1.0f;
  int k0 = ks * 32 + lg * 8, h = n & (HH - 1);
  bf16x8 r;
#pragma unroll
  for (int j = 0; j < 8; ++j) r[j] = f2bf(W[(k0 + j) * HH + h] * sc);
  *(bf16x8*)(WtF + (size_t)idx * 8) = r;
}

// ---------------- proj32: 32-row blocks, single stage, dbuf MFMA -------------
// grid 512 (32 rows/block), 256 thr (4 waves), 64 KB LDS -> 2 blocks/CU.
// Stage: x[32][1024] f32 -> bf16 frag-order swizzled LDS (two 32KB halves,
// group g = rows 16g..16g+15). Loop: v14's wA/wB double-buffer, 32 ks,
// 2 A-frags (one per group) x 3 nf -> 6 MFMA/iter; WtF bytes amortized
// over 2x rows. Epilogue: v15's verified 32-row kF/vF emission.
__launch_bounds__(256, 2)
__global__ void proj_kernel(const float* __restrict__ x, const short* __restrict__ WtF,
                            short* __restrict__ qo, short* __restrict__ kFo,
                            short* __restrict__ vFo) {
  __shared__ __align__(16) short xs[32 * 1024];   // 64 KB (reused by epilogue)
  int t = threadIdx.x;
  int row0 = blockIdx.x * 32;

  {  // stage: thread = (row r32 = t>>3, kc = t&7); 16 chunks c = kc + i*8
    int r32 = t >> 3, kc = t & 7;
    int g = r32 >> 4, r = r32 & 15;
    const float4* xr4 = (const float4*)(x + (size_t)(row0 + r32) * CC);
#pragma unroll
    for (int i = 0; i < 16; ++i) {
      int c = kc + i * 8;
      float4 a = xr4[c * 2], b2 = xr4[c * 2 + 1];
      uint4 w;
      w.x = pk2bf(a.x, a.y);   w.y = pk2bf(a.z, a.w);
      w.z = pk2bf(b2.x, b2.y); w.w = pk2bf(b2.z, b2.w);
      int S = g * 32768 + ((c * 256 + r * 16) ^ ((c & 7) << 4));
      *(uint4*)((char*)xs + S) = w;
    }
  }
  __syncthreads();

  int wave = t >> 6, lane = t & 63;
  int l15 = lane & 15, lg = lane >> 4;
  int nf0 = wave * 3;
  const short* wp = WtF + ((size_t)nf0 * 32 * 64 + (size_t)lane) * 8;
  const char* xsb = (const char*)xs;

  f32x4 acc[2][3];
#pragma unroll
  for (int g = 0; g < 2; ++g)
#pragma unroll
    for (int j = 0; j < 3; ++j) acc[g][j] = (f32x4){0.f, 0.f, 0.f, 0.f};

  bf16x8 wA[3], wB[3];
#pragma unroll
  for (int j = 0; j < 3; ++j) wA[j] = *(const bf16x8*)(wp + (size_t)j * 32 * 512);

#pragma unroll
  for (int ks = 0; ks < 32; ks += 2) {
#pragma unroll
    for (int j = 0; j < 3; ++j)
      wB[j] = *(const bf16x8*)(wp + ((size_t)j * 32 + ks + 1) * 512);
    int sw0 = ks * 1024 + ((lane * 16) ^ ((((ks * 4) + lg) & 7) << 4));
    bf16x8 a0g0 = *(const bf16x8*)(xsb + sw0);
    bf16x8 a0g1 = *(const bf16x8*)(xsb + 32768 + sw0);
#pragma unroll
    for (int j = 0; j < 3; ++j) {
      acc[0][j] = __builtin_amdgcn_mfma_f32_16x16x32_bf16(a0g0, wA[j], acc[0][j], 0, 0, 0);
      acc[1][j] = __builtin_amdgcn_mfma_f32_16x16x32_bf16(a0g1, wA[j], acc[1][j], 0, 0, 0);
    }
    if (ks + 2 < 32) {
#pragma unroll
      for (int j = 0; j < 3; ++j)
        wA[j] = *(const bf16x8*)(wp + ((size_t)j * 32 + ks + 2) * 512);
    }
    int sw1 = (ks + 1) * 1024 + ((lane * 16) ^ (((((ks + 1) * 4) + lg) & 7) << 4));
    bf16x8 a1g0 = *(const bf16x8*)(xsb + sw1);
    bf16x8 a1g1 = *(const bf16x8*)(xsb + 32768 + sw1);
#pragma unroll
    for (int j = 0; j < 3; ++j) {
      acc[0][j] = __builtin_amdgcn_mfma_f32_16x16x32_bf16(a1g0, wB[j], acc[0][j], 0, 0, 0);
      acc[1][j] = __builtin_amdgcn_mfma_f32_16x16x32_bf16(a1g1, wB[j], acc[1][j], 0, 0, 0);
    }
  }

  // ---- epilogue (v15-verified): q row-major; k/v via LDS -> kF/vF ----
  __syncthreads();           // xs staging data dead; reuse
#pragma unroll
  for (int g = 0; g < 2; ++g) {
    int row0g = row0 + g * 16;
    short* kslg = xs + g * 1152;          // [16 rows][72]
    short* vslg = xs + 2304 + g * 1536;   // [64 h][24]
#pragma unroll
    for (int j = 0; j < 3; ++j) {
      int nf = nf0 + j;
      int h = (nf & 3) * 16 + l15;
      if (nf < 4) {          // q: row-major global
#pragma unroll
        for (int reg = 0; reg < 4; ++reg)
          qo[(size_t)(row0g + lg * 4 + reg) * HH + h] = f2bf(acc[g][j][reg]);
      } else if (nf < 8) {   // k: stage [row][h], stride 72
#pragma unroll
        for (int reg = 0; reg < 4; ++reg)
          kslg[(lg * 4 + reg) * 72 + h] = f2bf(acc[g][j][reg]);
      } else {               // v: stage transposed [h][row], packed
        uint2 w2;
        w2.x = pk2bf(acc[g][j][0], acc[g][j][1]);
        w2.y = pk2bf(acc[g][j][2], acc[g][j][3]);
        *(uint2*)(vslg + h * 24 + lg * 4) = w2;
      }
    }
  }
  __syncthreads();

#pragma unroll
  for (int g = 0; g < 2; ++g) {
    int row0g = row0 + g * 16;
    int b = row0g >> 12;
    int kt = (row0g & 4095) >> 6;
    int cf = (row0g >> 4) & 3;
    const short* kslg = xs + g * 1152;
    const short* vslg = xs + 2304 + g * 1536;
    size_t tileoff = ((size_t)b * 64 + kt) * 4096;
    if (t < 128) {           // kF chunks ld = cf*2 + ks2 (full)
      int ks2 = t >> 6, ln = t & 63;
      int l15o = ln & 15, lgo = ln >> 4;
      bf16x8 r = *(const bf16x8*)(kslg + l15o * 72 + ks2 * 32 + lgo * 8);
      *(bf16x8*)(kFo + tileoff + (size_t)(cf * 2 + ks2) * 512 + ln * 8) = r;
    } else if (t < 256) {    // vF chunks ld = hf*2 + (cf>>1), lanes lg-subset
      int t2 = t - 128;
      int hf = t2 >> 5, lgl = (t2 >> 4) & 1, l15o = t2 & 15;
      bf16x8 r = *(const bf16x8*)(vslg + (hf * 16 + l15o) * 24 + lgl * 8);
      int lnout = (2 * (cf & 1) + lgl) * 16 + l15o;
      *(bf16x8*)(vFo + tileoff + (size_t)(hf * 2 + (cf >> 1)) * 512 + lnout * 8) = r;
    }
  }
}

// ---------------- attnW: swapped QK^T + packed P writes ----------------------
// (byte-identical to v15/v16/v17)
__launch_bounds__(512, 4)
__global__ void attnW_kernel(const short* __restrict__ q, const short* __restrict__ kF,
                             const short* __restrict__ vF, float* __restrict__ out) {
  __shared__ __align__(16) short ps[8][2560];     // 20 KB: 2 P-tiles/wave, 80B rows
  __shared__ __align__(16) float macc[32][68];    // 8.7 KB merge O
  __shared__ float lL[32];
  int wave = threadIdx.x >> 6, lane = threadIdx.x & 63;
  int l15 = lane & 15, lg = lane >> 4;
  int low3 = blockIdx.x & 7;                 // XCD id (perf heuristic only)
  int b  = low3 >> 1;                        // 2 XCDs per batch -> L2-resident KV
  int qt = ((blockIdx.x >> 3) << 1) | (low3 & 1);   // 0..127
  int brow0 = qt * 32;

  const short* qb = q + ((size_t)b * TT + brow0 + l15) * HH;
  bf16x8 qa[2][2];
#pragma unroll
  for (int g = 0; g < 2; ++g) {
    qa[g][0] = *(const bf16x8*)(qb + g * 16 * HH + lg * 8);
    qa[g][1] = *(const bf16x8*)(qb + g * 16 * HH + 32 + lg * 8);
  }

  bf16x8 ones;
#pragma unroll
  for (int j = 0; j < 8; ++j) ones[j] = (short)0x3F80;   // bf16 1.0

  const short* kfb = kF + (size_t)b * 262144 + (size_t)lane * 8;
  const short* vfb = vF + (size_t)b * 262144 + (size_t)lane * 8;

  f32x4 acc[2][4], accl[2];
#pragma unroll
  for (int g = 0; g < 2; ++g) {
#pragma unroll
    for (int i = 0; i < 4; ++i) acc[g][i] = (f32x4){0.f, 0.f, 0.f, 0.f};
    accl[g] = (f32x4){0.f, 0.f, 0.f, 0.f};
  }

  char* psw = (char*)&ps[wave][0];
  int xorv = (l15 >> 3) << 4;
  int pwbase = l15 * 80;                       // write row = l15 (qrow)
  int pr = l15 * 80 + ((lg << 4) ^ xorv);      // read: row=l15, colbytes lg*16..+15

  for (int t = wave * 16; t < wave * 16 + 16; ++t) {
    const short* kp = kfb + (size_t)t * 2048;
    const short* vp = vfb + (size_t)(t >> 1) * 4096 + (size_t)(t & 1) * 512;
    bf16x8 kf[4], vf[4];
#pragma unroll
    for (int ld = 0; ld < 4; ++ld) kf[ld] = *(const bf16x8*)(kp + ld * 512);
#pragma unroll
    for (int hf = 0; hf < 4; ++hf) vf[hf] = *(const bf16x8*)(vp + hf * 1024);
    // ---- S^T = K q^T (kv on reg axis); p = exp2; packed pair writes ----
#pragma unroll
    for (int g = 0; g < 2; ++g)
#pragma unroll
      for (int cf = 0; cf < 2; ++cf) {
        f32x4 t4 = (f32x4){0.f, 0.f, 0.f, 0.f};
        t4 = __builtin_amdgcn_mfma_f32_16x16x32_bf16(kf[cf * 2], qa[g][0], t4, 0, 0, 0);
        t4 = __builtin_amdgcn_mfma_f32_16x16x32_bf16(kf[cf * 2 + 1], qa[g][1], t4, 0, 0, 0);
        float p0 = EXP2(t4[0]), p1 = EXP2(t4[1]);
        float p2 = EXP2(t4[2]), p3 = EXP2(t4[3]);
        unsigned w01 = pk2bf(p0, p1);
        unsigned w23 = pk2bf(p2, p3);
        int cb = (cf << 5) + (lg << 3);        // column byte = kv*2
        *(unsigned*)(psw + g * 1280 + pwbase + ((cb) ^ xorv)) = w01;
        *(unsigned*)(psw + g * 1280 + pwbase + ((cb + 4) ^ xorv)) = w23;
      }
    // ---- O += P V ; l += P . 1 ----
    bf16x8 pa0 = *(const bf16x8*)(psw + pr);
    bf16x8 pa1 = *(const bf16x8*)(psw + 1280 + pr);
    __builtin_amdgcn_s_setprio(1);
#pragma unroll
    for (int hf = 0; hf < 4; ++hf) {
      acc[0][hf] = __builtin_amdgcn_mfma_f32_16x16x32_bf16(pa0, vf[hf], acc[0][hf], 0, 0, 0);
      acc[1][hf] = __builtin_amdgcn_mfma_f32_16x16x32_bf16(pa1, vf[hf], acc[1][hf], 0, 0, 0);
    }
    accl[0] = __builtin_amdgcn_mfma_f32_16x16x32_bf16(pa0, ones, accl[0], 0, 0, 0);
    accl[1] = __builtin_amdgcn_mfma_f32_16x16x32_bf16(pa1, ones, accl[1], 0, 0, 0);
    __builtin_amdgcn_s_setprio(0);
  }

  // ---- merge 8 KV-eighths: sequential-barrier LDS accumulation ----
#pragma unroll
  for (int ph = 0; ph < 8; ++ph) {
    if (wave == ph) {
#pragma unroll
      for (int g = 0; g < 2; ++g)
#pragma unroll
        for (int reg = 0; reg < 4; ++reg) {
          int row = g * 16 + lg * 4 + reg;
          if (ph == 0) {
#pragma unroll
            for (int hf = 0; hf < 4; ++hf)
              macc[row][hf * 16 + l15] = acc[g][hf][reg];
            if (l15 == 0) lL[row] = accl[g][reg];
          } else {
#pragma unroll
            for (int hf = 0; hf < 4; ++hf)
              macc[row][hf * 16 + l15] += acc[g][hf][reg];
            if (l15 == 0) lL[row] += accl[g][reg];
          }
        }
    }
    __syncthreads();
  }

  // ---- normalize + store (32 rows x 64 cols = 4 f32/thread) ----
  {
    int tt = threadIdx.x;
    int r = tt >> 4, c0 = (tt & 15) * 4;
    float linv = 1.0f / lL[r];
    float4 o;
    o.x = macc[r][c0 + 0] * linv; o.y = macc[r][c0 + 1] * linv;
    o.z = macc[r][c0 + 2] * linv; o.w = macc[r][c0 + 3] * linv;
    *(float4*)(out + ((size_t)b * TT + brow0 + r) * HH + c0) = o;
  }
}

extern "C" void kernel_launch(void* const* d_in, const int* in_sizes, int n_in,
                              void* d_out, int out_size, void* d_ws, size_t ws_size,
                              hipStream_t stream) {
  const float* x  = (const float*)d_in[0];
  const float* Wq = (const float*)d_in[1];
  const float* Wk = (const float*)d_in[2];
  const float* Wv = (const float*)d_in[3];
  float* out = (float*)d_out;

  char* ws = (char*)d_ws;
  short* WtF = (short*)ws;                 // 384 KB (pad to 512K)
  short* q   = (short*)(ws + 0x080000);    // 2 MB
  short* kF  = (short*)(ws + 0x280000);    // 2 MB
  short* vF  = (short*)(ws + 0x480000);    // 2 MB -> 6.5 MB total

  hipLaunchKernelGGL(wtf_kernel,   dim3(96),  dim3(256), 0, stream, Wq, Wk, Wv, WtF);
  hipLaunchKernelGGL(proj_kernel,  dim3(512), dim3(256), 0, stream, x, WtF, q, kF, vF);
  hipLaunchKernelGGL(attnW_kernel, dim3(512), dim3(512), 0, stream, q, kF, vF, out);
}